// Round 1
// baseline (177.646 us; speedup 1.0000x reference)
//
#include <hip/hip_runtime.h>

using f16   = _Float16;
using f16x4 = __attribute__((ext_vector_type(4))) _Float16;
using f16x8 = __attribute__((ext_vector_type(8))) _Float16;
using f32x4 = __attribute__((ext_vector_type(4))) float;

#define NBATCH 8
#define TQ 2048
#define TK 4096
#define DD 128
#define QBLK 64
#define KBLK 128
#define NTILES (TK / KBLK)
#define CTX_ELEMS ((size_t)NBATCH * TQ * DD)

// K tile, [128 tok][128 d] f16, 16x16 subtiles, row-XOR by d-subtile so that
// staging writes (same tok, 8 d-subtiles) and QK B-frag reads are conflict-free.
__device__ __forceinline__ int kidx(int t, int d) {
    return (((t >> 4) << 3) + (d >> 4)) * 256 + (((t & 15) ^ ((d >> 4) & 7)) << 4) + (d & 15);
}
// V^T tile, [128 d][128 tok] f16, 16x16 subtiles, row-XOR by d-subtile.
__device__ __forceinline__ int vidx(int d, int t) {
    return (((d >> 4) << 3) + (t >> 4)) * 256 + (((d & 15) ^ ((d >> 4) & 7)) << 4) + (t & 15);
}

__global__ __launch_bounds__(512, 2)
void luong_attn_kernel(const float* __restrict__ dec,
                       const float* __restrict__ enc,
                       float* __restrict__ out) {
    __shared__ f16 Klds[KBLK * DD];          // 32 KB
    __shared__ f16 VTlds[DD * KBLK];         // 32 KB
    __shared__ f16 Plds[8][4 * 256];         // 16 KB, per-wave P (16q x 64t, subtiled)
    __shared__ float SMm[8][16];
    __shared__ float SMz[8][16];

    const int tid  = threadIdx.x;
    const int wid  = tid >> 6;
    const int lane = tid & 63;
    const int lo   = lane & 15;
    const int g    = lane >> 4;
    const int qg   = wid & 3;   // q sub-block (16 rows each)
    const int kh   = wid >> 2;  // token half of each 128-tile

    const int b     = blockIdx.x & 7;         // XCD swizzle: one batch per XCD
    const int qbase = (blockIdx.x >> 3) * QBLK;

    const float* encB = enc + ((size_t)b * TK) * DD;
    float* attn_out = out + CTX_ELEMS;

    // ---- Q fragments, A layout: row = lo, k = 32*kk + 8*g + j ----
    const int qrow = qbase + qg * 16 + lo;
    const float* qp = dec + ((size_t)b * TQ + qrow) * DD;
    f16x8 qf[4];
    #pragma unroll
    for (int kk = 0; kk < 4; ++kk) {
        const float4 x = *(const float4*)(qp + kk * 32 + g * 8);
        const float4 y = *(const float4*)(qp + kk * 32 + g * 8 + 4);
        f16x8 h;
        h[0] = (f16)x.x; h[1] = (f16)x.y; h[2] = (f16)x.z; h[3] = (f16)x.w;
        h[4] = (f16)y.x; h[5] = (f16)y.y; h[6] = (f16)y.z; h[7] = (f16)y.w;
        qf[kk] = h;
    }

    float m[4], Z[4];
    #pragma unroll
    for (int r = 0; r < 4; ++r) { m[r] = -INFINITY; Z[r] = 0.0f; }

    // ===================== PASS 1: online softmax stats =====================
    #pragma unroll 1
    for (int tile = 0; tile < NTILES; ++tile) {
        const float* src = encB + (size_t)tile * KBLK * DD;
        #pragma unroll
        for (int i = 0; i < 8; ++i) {
            const int idx = tid + (i << 9);
            const int t = idx >> 5;
            const int d = (idx & 31) << 2;
            const float4 v = *(const float4*)(src + t * DD + d);
            f16x4 h;
            h[0] = (f16)v.x; h[1] = (f16)v.y; h[2] = (f16)v.z; h[3] = (f16)v.w;
            *(f16x4*)&Klds[kidx(t, d)] = h;
        }
        __syncthreads();

        f32x4 S[4];
        #pragma unroll
        for (int f = 0; f < 4; ++f) { f32x4 z = {0.f, 0.f, 0.f, 0.f}; S[f] = z; }
        #pragma unroll
        for (int f = 0; f < 4; ++f) {
            const int t = kh * 64 + f * 16 + lo;
            #pragma unroll
            for (int kk = 0; kk < 4; ++kk) {
                const f16x8 bf = *(const f16x8*)&Klds[kidx(t, kk * 32 + g * 8)];
                S[f] = __builtin_amdgcn_mfma_f32_16x16x32_f16(qf[kk], bf, S[f], 0, 0, 0);
            }
        }

        #pragma unroll
        for (int r = 0; r < 4; ++r) {
            float mt = fmaxf(fmaxf(S[0][r], S[1][r]), fmaxf(S[2][r], S[3][r]));
            mt = fmaxf(mt, __shfl_xor(mt, 1));
            mt = fmaxf(mt, __shfl_xor(mt, 2));
            mt = fmaxf(mt, __shfl_xor(mt, 4));
            mt = fmaxf(mt, __shfl_xor(mt, 8));
            const float mn = fmaxf(m[r], mt);
            float s = __expf(S[0][r] - mn) + __expf(S[1][r] - mn)
                    + __expf(S[2][r] - mn) + __expf(S[3][r] - mn);
            s += __shfl_xor(s, 1); s += __shfl_xor(s, 2);
            s += __shfl_xor(s, 4); s += __shfl_xor(s, 8);
            Z[r] = Z[r] * __expf(m[r] - mn) + s;
            m[r] = mn;
        }
        __syncthreads();
    }

    // combine the two k-halves (wave pairs wid, wid^4 share the q sub-block)
    if (lo == 0) {
        #pragma unroll
        for (int r = 0; r < 4; ++r) { SMm[wid][4 * g + r] = m[r]; SMz[wid][4 * g + r] = Z[r]; }
    }
    __syncthreads();
    #pragma unroll
    for (int r = 0; r < 4; ++r) {
        const float mo = SMm[wid ^ 4][4 * g + r];
        const float zo = SMz[wid ^ 4][4 * g + r];
        const float M  = fmaxf(m[r], mo);
        const float z  = Z[r] * __expf(m[r] - M) + zo * __expf(mo - M);
        m[r] = M;
        Z[r] = 1.0f / z;   // Z now holds 1/denominator
    }
    __syncthreads();

    // ===================== PASS 2: write attention + PV =====================
    f32x4 ctx[8];
    #pragma unroll
    for (int n = 0; n < 8; ++n) { f32x4 z = {0.f, 0.f, 0.f, 0.f}; ctx[n] = z; }

    #pragma unroll 1
    for (int tile = 0; tile < NTILES; ++tile) {
        const float* src = encB + (size_t)tile * KBLK * DD;
        #pragma unroll
        for (int i = 0; i < 8; ++i) {
            const int idx = tid + (i << 9);
            const int t = idx >> 5;
            const int d = (idx & 31) << 2;
            const float4 v = *(const float4*)(src + t * DD + d);
            f16x4 h;
            h[0] = (f16)v.x; h[1] = (f16)v.y; h[2] = (f16)v.z; h[3] = (f16)v.w;
            *(f16x4*)&Klds[kidx(t, d)] = h;
            VTlds[vidx(d + 0, t)] = h[0];
            VTlds[vidx(d + 1, t)] = h[1];
            VTlds[vidx(d + 2, t)] = h[2];
            VTlds[vidx(d + 3, t)] = h[3];
        }
        __syncthreads();

        f32x4 S[4];
        #pragma unroll
        for (int f = 0; f < 4; ++f) { f32x4 z = {0.f, 0.f, 0.f, 0.f}; S[f] = z; }
        #pragma unroll
        for (int f = 0; f < 4; ++f) {
            const int t = kh * 64 + f * 16 + lo;
            #pragma unroll
            for (int kk = 0; kk < 4; ++kk) {
                const f16x8 bf = *(const f16x8*)&Klds[kidx(t, kk * 32 + g * 8)];
                S[f] = __builtin_amdgcn_mfma_f32_16x16x32_f16(qf[kk], bf, S[f], 0, 0, 0);
            }
        }

        f16* Pw = Plds[wid];
        #pragma unroll
        for (int f = 0; f < 4; ++f) {
            const int t = tile * KBLK + kh * 64 + f * 16 + lo;
            #pragma unroll
            for (int r = 0; r < 4; ++r) {
                const int q = qbase + qg * 16 + 4 * g + r;
                const float p = __expf(S[f][r] - m[r]) * Z[r];
                __builtin_nontemporal_store(p, attn_out + ((size_t)b * TQ + q) * TK + t);
                Pw[f * 256 + (4 * g + r) * 16 + lo] = (f16)p;   // [tblk][q][t&15]
            }
        }

        #pragma unroll
        for (int ks = 0; ks < 2; ++ks) {
            const int tl = ks * 32 + g * 8;
            const f16x8 pa = *(const f16x8*)&Pw[(tl >> 4) * 256 + lo * 16 + (tl & 15)];
            #pragma unroll
            for (int n = 0; n < 8; ++n) {
                const f16x8 vb = *(const f16x8*)&VTlds[vidx(n * 16 + lo, kh * 64 + tl)];
                ctx[n] = __builtin_amdgcn_mfma_f32_16x16x32_f16(pa, vb, ctx[n], 0, 0, 0);
            }
        }
        __syncthreads();
    }

    // ---- combine the two k-half context partials and store ----
    float* CT = (float*)Klds;   // 64 q x 128 d floats = 32 KB
    if (kh == 0) {
        #pragma unroll
        for (int n = 0; n < 8; ++n)
            #pragma unroll
            for (int r = 0; r < 4; ++r)
                CT[(qg * 16 + 4 * g + r) * DD + n * 16 + lo] = ctx[n][r];
    }
    __syncthreads();
    if (kh == 1) {
        #pragma unroll
        for (int n = 0; n < 8; ++n)
            #pragma unroll
            for (int r = 0; r < 4; ++r) {
                const int q = qbase + qg * 16 + 4 * g + r;
                const float v = ctx[n][r] + CT[(qg * 16 + 4 * g + r) * DD + n * 16 + lo];
                out[((size_t)b * TQ + q) * DD + n * 16 + lo] = v;
            }
    }
}

extern "C" void kernel_launch(void* const* d_in, const int* in_sizes, int n_in,
                              void* d_out, int out_size, void* d_ws, size_t ws_size,
                              hipStream_t stream) {
    (void)in_sizes; (void)n_in; (void)out_size; (void)d_ws; (void)ws_size;
    const float* dec = (const float*)d_in[0];
    const float* enc = (const float*)d_in[1];
    float* out = (float*)d_out;
    dim3 grid(NBATCH * (TQ / QBLK));   // 256 blocks = 1/CU; bid&7 = batch = XCD
    dim3 block(512);                   // 8 waves: 4 q-subtiles x 2 k-halves
    hipLaunchKernelGGL(luong_attn_kernel, grid, block, 0, stream, dec, enc, out);
}